// Round 6
// baseline (305.835 us; speedup 1.0000x reference)
//
#include <hip/hip_runtime.h>
#include <hip/hip_fp16.h>

// B=4, T=2048, C=1024. Single-head causal attention, fp32 in/out.
// Internals fp16 (MFMA f32_16x16x32_f16), fp32 accum + fp32 softmax.
// R6: VMEM-intensity restructure. qkv/scores: 256x128 tiles (192 staged
// B/MFMA, ceiling ~40% vs 256 B/MFMA ~30%). pv: 128x128 @ 3 blocks/CU.
// Generalized wave grid (WM x WN waves of EM x EN each). BK=64.

typedef __attribute__((ext_vector_type(8))) _Float16 half8;
typedef __attribute__((ext_vector_type(4))) _Float16 half4;
typedef __attribute__((ext_vector_type(4))) float f32x4;

#define AS1 __attribute__((address_space(1)))
#define AS3 __attribute__((address_space(3)))

__device__ __forceinline__ void gload_lds16(const void* g, void* l) {
    __builtin_amdgcn_global_load_lds((AS1 void*)g, (AS3 void*)l, 16, 0, 0);
}

// ---------------------------------------------------------------------------
// NT-GEMM core, TM x TN tile, BK=64, 256 thr = WM*WN waves; wave (wm,wn)
// computes EM x EN = (TM/WM) x (TN/WN) via FM x FN 16x16x32 MFMA frags.
// A[m][k] lda, B[n][k] ldb, k in [k0,k1) mult of 64.
// LDS swizzle (R2/R5-verified 0 conflicts): 128B rows of 8 chunks;
// chunk f holds global (row=f>>3, colchunk=(f&7)^((f>>3)&7)); fragment
// (row R, k-half h, lq) at chunk 8R + ((h*4+lq)^(R&7)).
// SWAP: mfma(b,a) -> C^T frags (4 consecutive n-cols per lane).
// ---------------------------------------------------------------------------
template<int TM, int TN, int WM, int WN, bool SWAP>
__device__ __forceinline__ void gemm_nt_core(
    const _Float16* __restrict__ A, const _Float16* __restrict__ B,
    int lda, int ldb, int k0, int k1,
    _Float16* ldsA, _Float16* ldsB,      // TM*64, TN*64 halves
    f32x4 acc[TM / (WM * 16)][TN / (WN * 16)])
{
    constexpr int FM = TM / (WM * 16), FN = TN / (WN * 16);
    constexpr int NA = TM / 32, NB = TN / 32;   // 16B chunks per thread
    const int t    = threadIdx.x;
    const int lane = t & 63;
    const int w    = t >> 6;
    const int wm   = w % WM;
    const int wn   = w / WM;
    const int lr   = lane & 15;
    const int lq   = lane >> 4;

    const _Float16* ga[NA]; int loA[NA];
    const _Float16* gb[NB]; int loB[NB];
#pragma unroll
    for (int i = 0; i < NA; ++i) {
        int f = t + 256 * i;
        int r = f >> 3, c = (f & 7) ^ ((f >> 3) & 7);
        ga[i] = A + (size_t)r * lda + c * 8;
        loA[i] = f * 8;
    }
#pragma unroll
    for (int i = 0; i < NB; ++i) {
        int f = t + 256 * i;
        int r = f >> 3, c = (f & 7) ^ ((f >> 3) & 7);
        gb[i] = B + (size_t)r * ldb + c * 8;
        loB[i] = f * 8;
    }

    int offA[2][FM], offB[2][FN];
#pragma unroll
    for (int h = 0; h < 2; ++h) {
#pragma unroll
        for (int i = 0; i < FM; ++i) {
            int R = wm * (TM / WM) + i * 16 + lr;
            offA[h][i] = (8 * R + ((h * 4 + lq) ^ (R & 7))) * 8;
        }
#pragma unroll
        for (int i = 0; i < FN; ++i) {
            int R = wn * (TN / WN) + i * 16 + lr;
            offB[h][i] = (8 * R + ((h * 4 + lq) ^ (R & 7))) * 8;
        }
    }

    for (int k = k0; k < k1; k += 64) {
        __syncthreads();
#pragma unroll
        for (int i = 0; i < NA; ++i) gload_lds16(ga[i] + k, ldsA + loA[i]);
#pragma unroll
        for (int i = 0; i < NB; ++i) gload_lds16(gb[i] + k, ldsB + loB[i]);
        __syncthreads();

#pragma unroll
        for (int h = 0; h < 2; ++h) {
            half8 af[FM], bf[FN];
#pragma unroll
            for (int i = 0; i < FM; ++i) af[i] = *(const half8*)(ldsA + offA[h][i]);
#pragma unroll
            for (int i = 0; i < FN; ++i) bf[i] = *(const half8*)(ldsB + offB[h][i]);
#pragma unroll
            for (int mi = 0; mi < FM; ++mi)
#pragma unroll
                for (int ni = 0; ni < FN; ++ni) {
                    if constexpr (SWAP)
                        acc[mi][ni] = __builtin_amdgcn_mfma_f32_16x16x32_f16(
                            bf[ni], af[mi], acc[mi][ni], 0, 0, 0);
                    else
                        acc[mi][ni] = __builtin_amdgcn_mfma_f32_16x16x32_f16(
                            af[mi], bf[ni], acc[mi][ni], 0, 0, 0);
                }
        }
    }
}

// ---------------------------------------------------------------------------
__global__ __launch_bounds__(256) void f32tof16_k(
    const float* __restrict__ in, _Float16* __restrict__ out, int n)
{
    int i = (blockIdx.x * 256 + threadIdx.x) * 4;
    if (i < n) {
        float4 f = *(const float4*)(in + i);
        half4 h = { (_Float16)f.x, (_Float16)f.y, (_Float16)f.z, (_Float16)f.w };
        *(half4*)(out + i) = h;
    }
}

__global__ __launch_bounds__(256) void wconv_k(
    const float* __restrict__ Wq, const float* __restrict__ Wk,
    const float* __restrict__ Wv, _Float16* __restrict__ out)
{
    const float* src = (blockIdx.y == 0) ? Wq : (blockIdx.y == 1) ? Wk : Wv;
    int i = (blockIdx.x * 256 + threadIdx.x) * 4;
    float4 f = *(const float4*)(src + i);
    half4 h = { (_Float16)f.x, (_Float16)f.y, (_Float16)f.z, (_Float16)f.w };
    *(half4*)(out + (size_t)blockIdx.y * 1024 * 1024 + i) = h;
}

// ---------------------------------------------------------------------------
// Fused QKV: 256(m)x128(n) tiles, 4 waves of 64x128, grid (32,8,3) = 768.
// z=0 Q[t][d], z=1 K[s][d] (swapped, half4 along d); z=2 Vt[b][d][t]
// (unswapped, half4 along t).
// ---------------------------------------------------------------------------
__global__ __launch_bounds__(256) void qkv_gemm_k(
    const _Float16* __restrict__ xh, const _Float16* __restrict__ Wh,
    _Float16* __restrict__ Q, _Float16* __restrict__ K, _Float16* __restrict__ Vt)
{
    __shared__ __align__(16) _Float16 ldsA[256 * 64];   // 32 KB
    __shared__ __align__(16) _Float16 ldsB[128 * 64];   // 16 KB
    const int tileM = blockIdx.x * 256;
    const int tileN = blockIdx.y * 128;
    const int z     = blockIdx.z;
    const _Float16* W = Wh + (size_t)z * 1024 * 1024;

    const int lane = threadIdx.x & 63;
    const int wm   = threadIdx.x >> 6;     // WM=4, WN=1
    const int lr = lane & 15, lq = lane >> 4;

    if (z == 2) {
        f32x4 acc[4][8] = {};
        gemm_nt_core<256, 128, 4, 1, false>(xh + (size_t)tileM * 1024,
                                            W + (size_t)tileN * 1024,
                                            1024, 1024, 0, 1024, ldsA, ldsB, acc);
#pragma unroll
        for (int mi = 0; mi < 4; ++mi)
#pragma unroll
            for (int ni = 0; ni < 8; ++ni) {
                int m0 = tileM + wm * 64 + mi * 16 + lq * 4;
                int n  = tileN + ni * 16 + lr;
                int b = m0 >> 11, tt = m0 & 2047;
                half4 h = { (_Float16)acc[mi][ni][0], (_Float16)acc[mi][ni][1],
                            (_Float16)acc[mi][ni][2], (_Float16)acc[mi][ni][3] };
                *(half4*)(Vt + (size_t)b * 2048 * 1024 + (size_t)n * 2048 + tt) = h;
            }
    } else {
        f32x4 acc[4][8] = {};
        gemm_nt_core<256, 128, 4, 1, true>(xh + (size_t)tileM * 1024,
                                           W + (size_t)tileN * 1024,
                                           1024, 1024, 0, 1024, ldsA, ldsB, acc);
        _Float16* O = (z == 0) ? Q : K;
#pragma unroll
        for (int mi = 0; mi < 4; ++mi)
#pragma unroll
            for (int ni = 0; ni < 8; ++ni) {
                int tt = tileM + wm * 64 + mi * 16 + lr;
                int d0 = tileN + ni * 16 + lq * 4;
                half4 h = { (_Float16)acc[mi][ni][0], (_Float16)acc[mi][ni][1],
                            (_Float16)acc[mi][ni][2], (_Float16)acc[mi][ni][3] };
                *(half4*)(O + (size_t)tt * 1024 + d0) = h;
            }
    }
}

// ---------------------------------------------------------------------------
// Scores (fp16): 256(t)x128(s) tiles, grid (8,16,4), keep si <= 2*ti+1.
// Swapped MFMA -> half4 along s, causal mask to 0 in-tile.
// ---------------------------------------------------------------------------
__global__ __launch_bounds__(256) void scores_gemm_k(
    const _Float16* __restrict__ Q, const _Float16* __restrict__ K,
    _Float16* __restrict__ S)
{
    const int ti = blockIdx.x, si = blockIdx.y;
    if (si > 2 * ti + 1) return;             // fully above diagonal
    const int tileT = ti * 256, tileS = si * 128, b = blockIdx.z;

    __shared__ __align__(16) _Float16 ldsA[256 * 64];
    __shared__ __align__(16) _Float16 ldsB[128 * 64];
    f32x4 acc[4][8] = {};
    gemm_nt_core<256, 128, 4, 1, true>(
        Q + (size_t)b * 2048 * 1024 + (size_t)tileT * 1024,
        K + (size_t)b * 2048 * 1024 + (size_t)tileS * 1024,
        1024, 1024, 0, 1024, ldsA, ldsB, acc);

    const int lane = threadIdx.x & 63;
    const int wm   = threadIdx.x >> 6;
    const int lr = lane & 15, lq = lane >> 4;
    const float scale = 0.03125f;  // 1024^-0.5

#pragma unroll
    for (int mi = 0; mi < 4; ++mi)
#pragma unroll
        for (int ni = 0; ni < 8; ++ni) {
            int tt = tileT + wm * 64 + mi * 16 + lr;
            int s0 = tileS + ni * 16 + lq * 4;
            half4 h;
#pragma unroll
            for (int r = 0; r < 4; ++r)
                h[r] = (s0 + r <= tt) ? (_Float16)(acc[mi][ni][r] * scale)
                                      : (_Float16)0.f;
            *(half4*)(S + ((size_t)b * 2048 + tt) * 2048 + s0) = h;
        }
}

// ---------------------------------------------------------------------------
// Softmax: one wave per row, half8 loads, 64-lane shuffle reduce, no LDS.
// Zero-fills s>t.
// ---------------------------------------------------------------------------
__global__ __launch_bounds__(256) void softmax_k(_Float16* __restrict__ S)
{
    const int w    = threadIdx.x >> 6;
    const int lane = threadIdx.x & 63;
    const int t    = blockIdx.x * 4 + w;
    const int b    = blockIdx.y;
    _Float16* row = S + ((size_t)b * 2048 + t) * 2048;

    float x[32];
    float mx = -1e30f;
#pragma unroll
    for (int j = 0; j < 4; ++j) {
        half8 h = *(const half8*)(row + j * 512 + lane * 8);
#pragma unroll
        for (int e = 0; e < 8; ++e) {
            int s = j * 512 + lane * 8 + e;
            float f = (s <= t) ? (float)h[e] : -1e30f;
            x[j * 8 + e] = f;
            mx = fmaxf(mx, f);
        }
    }
#pragma unroll
    for (int o = 32; o > 0; o >>= 1) mx = fmaxf(mx, __shfl_xor(mx, o));

    float sum = 0.f;
#pragma unroll
    for (int i = 0; i < 32; ++i) {
        float e = __expf(x[i] - mx);
        x[i] = e;
        sum += e;
    }
#pragma unroll
    for (int o = 32; o > 0; o >>= 1) sum += __shfl_xor(sum, o);
    const float inv = 1.0f / sum;

#pragma unroll
    for (int j = 0; j < 4; ++j) {
        half8 p;
#pragma unroll
        for (int e = 0; e < 8; ++e) p[e] = (_Float16)(x[j * 8 + e] * inv);
        *(half8*)(row + j * 512 + lane * 8) = p;
    }
}

// ---------------------------------------------------------------------------
// PV: 128x128 tiles (acc=64 -> ~3 blocks/CU, best latency hiding), grid
// (16,8,4) = 512, kEnd = tileT+128, longest-first (natural pairing balances
// CUs at 2 blocks each). Swapped MFMA -> float4 along d.
// ---------------------------------------------------------------------------
__global__ __launch_bounds__(256) void pv_gemm_k(
    const _Float16* __restrict__ P, const _Float16* __restrict__ Vt,
    float* __restrict__ out)
{
    __shared__ __align__(16) _Float16 ldsA[128 * 64];
    __shared__ __align__(16) _Float16 ldsB[128 * 64];
    const int tileT = (15 - blockIdx.x) * 128;   // longest-first
    const int tileD = blockIdx.y * 128;
    const int b     = blockIdx.z;
    const int kEnd  = tileT + 128;

    f32x4 acc[4][4] = {};
    gemm_nt_core<128, 128, 2, 2, true>(
        P + ((size_t)b * 2048 + tileT) * 2048,
        Vt + (size_t)b * 1024 * 2048 + (size_t)tileD * 2048,
        2048, 2048, 0, kEnd, ldsA, ldsB, acc);

    const int lane = threadIdx.x & 63;
    const int w    = threadIdx.x >> 6;
    const int wm = w % 2, wn = w / 2;
    const int lr = lane & 15, lq = lane >> 4;

#pragma unroll
    for (int mi = 0; mi < 4; ++mi)
#pragma unroll
        for (int ni = 0; ni < 4; ++ni) {
            int tt = tileT + wm * 64 + mi * 16 + lr;
            int d0 = tileD + wn * 64 + ni * 16 + lq * 4;
            *(f32x4*)(out + ((size_t)b * 2048 + tt) * 1024 + d0) = acc[mi][ni];
        }
}

// ---------------------------------------------------------------------------
extern "C" void kernel_launch(void* const* d_in, const int* in_sizes, int n_in,
                              void* d_out, int out_size, void* d_ws, size_t ws_size,
                              hipStream_t stream)
{
    const float* x  = (const float*)d_in[0];
    const float* Wq = (const float*)d_in[1];
    const float* Wk = (const float*)d_in[2];
    const float* Wv = (const float*)d_in[3];
    float* out = (float*)d_out;

    char* ws = (char*)d_ws;
    // layout (MB): xh 0..16 | Wh 16..22 | Q 22..38 | K 38..54 | Vt 54..70 |
    // S16 70..102 (P aliases S).  Total 102 MB.
    _Float16* xh = (_Float16*)(ws);
    _Float16* Wh = (_Float16*)(ws + (16u << 20));
    _Float16* Qh = (_Float16*)(ws + (22u << 20));
    _Float16* Kh = (_Float16*)(ws + (38u << 20));
    _Float16* Vt = (_Float16*)(ws + (54u << 20));
    _Float16* S  = (_Float16*)(ws + (70u << 20));

    f32tof16_k<<<8192, 256, 0, stream>>>(x, xh, 4 * 2048 * 1024);
    wconv_k<<<dim3(1024, 3), 256, 0, stream>>>(Wq, Wk, Wv, Wh);

    qkv_gemm_k<<<dim3(32, 8, 3), 256, 0, stream>>>(xh, Wh, Qh, Kh, Vt);

    scores_gemm_k<<<dim3(8, 16, 4), 256, 0, stream>>>(Qh, Kh, S);
    softmax_k<<<dim3(512, 4), 256, 0, stream>>>(S);
    pv_gemm_k<<<dim3(16, 8, 4), 256, 0, stream>>>(S, Vt, out);
}

// Round 7
// 287.494 us; speedup vs baseline: 1.0638x; 1.0638x over previous
//
#include <hip/hip_runtime.h>
#include <hip/hip_fp16.h>

// B=4, T=2048, C=1024. Single-head causal attention, fp32 in/out.
// Internals fp16 (MFMA f32_16x16x32_f16), fp32 accum + fp32 softmax.
// R7: revert to 128^2 tiles everywhere (R6's 256-tile hit the VGPR-128
// occupancy cliff). Scores split-K x2 (S1+S2 summed inside softmax);
// PV split-s x2 (half 0 -> d_out, half 1 -> fp16 partial + combine pass).

typedef __attribute__((ext_vector_type(8))) _Float16 half8;
typedef __attribute__((ext_vector_type(4))) _Float16 half4;
typedef __attribute__((ext_vector_type(4))) float f32x4;

#define AS1 __attribute__((address_space(1)))
#define AS3 __attribute__((address_space(3)))

__device__ __forceinline__ void gload_lds16(const void* g, void* l) {
    __builtin_amdgcn_global_load_lds((AS1 void*)g, (AS3 void*)l, 16, 0, 0);
}

// ---------------------------------------------------------------------------
// NT-GEMM core, TM x TN tile, BK=64, 256 thr = WM*WN waves; wave (wm,wn)
// computes (TM/WM) x (TN/WN) via FM x FN 16x16x32 MFMA frags.
// A[m][k] lda, B[n][k] ldb, k in [k0,k1) mult of 64.
// LDS swizzle (verified 0 conflicts R5): 128B rows of 8 chunks; chunk f
// holds global (row=f>>3, colchunk=(f&7)^((f>>3)&7)); fragment (row R,
// k-half h, lq) at chunk 8R + ((h*4+lq)^(R&7)).
// SWAP: mfma(b,a) -> C^T frags (4 consecutive n-cols per lane).
// ---------------------------------------------------------------------------
template<int TM, int TN, int WM, int WN, bool SWAP>
__device__ __forceinline__ void gemm_nt_core(
    const _Float16* __restrict__ A, const _Float16* __restrict__ B,
    int lda, int ldb, int k0, int k1,
    _Float16* ldsA, _Float16* ldsB,      // TM*64, TN*64 halves
    f32x4 acc[TM / (WM * 16)][TN / (WN * 16)])
{
    constexpr int FM = TM / (WM * 16), FN = TN / (WN * 16);
    constexpr int NA = TM / 32, NB = TN / 32;   // 16B chunks per thread
    const int t    = threadIdx.x;
    const int lane = t & 63;
    const int w    = t >> 6;
    const int wm   = w % WM;
    const int wn   = w / WM;
    const int lr   = lane & 15;
    const int lq   = lane >> 4;

    const _Float16* ga[NA]; int loA[NA];
    const _Float16* gb[NB]; int loB[NB];
#pragma unroll
    for (int i = 0; i < NA; ++i) {
        int f = t + 256 * i;
        int r = f >> 3, c = (f & 7) ^ ((f >> 3) & 7);
        ga[i] = A + (size_t)r * lda + c * 8;
        loA[i] = f * 8;
    }
#pragma unroll
    for (int i = 0; i < NB; ++i) {
        int f = t + 256 * i;
        int r = f >> 3, c = (f & 7) ^ ((f >> 3) & 7);
        gb[i] = B + (size_t)r * ldb + c * 8;
        loB[i] = f * 8;
    }

    int offA[2][FM], offB[2][FN];
#pragma unroll
    for (int h = 0; h < 2; ++h) {
#pragma unroll
        for (int i = 0; i < FM; ++i) {
            int R = wm * (TM / WM) + i * 16 + lr;
            offA[h][i] = (8 * R + ((h * 4 + lq) ^ (R & 7))) * 8;
        }
#pragma unroll
        for (int i = 0; i < FN; ++i) {
            int R = wn * (TN / WN) + i * 16 + lr;
            offB[h][i] = (8 * R + ((h * 4 + lq) ^ (R & 7))) * 8;
        }
    }

    for (int k = k0; k < k1; k += 64) {
        __syncthreads();
#pragma unroll
        for (int i = 0; i < NA; ++i) gload_lds16(ga[i] + k, ldsA + loA[i]);
#pragma unroll
        for (int i = 0; i < NB; ++i) gload_lds16(gb[i] + k, ldsB + loB[i]);
        __syncthreads();

#pragma unroll
        for (int h = 0; h < 2; ++h) {
            half8 af[FM], bf[FN];
#pragma unroll
            for (int i = 0; i < FM; ++i) af[i] = *(const half8*)(ldsA + offA[h][i]);
#pragma unroll
            for (int i = 0; i < FN; ++i) bf[i] = *(const half8*)(ldsB + offB[h][i]);
#pragma unroll
            for (int mi = 0; mi < FM; ++mi)
#pragma unroll
                for (int ni = 0; ni < FN; ++ni) {
                    if constexpr (SWAP)
                        acc[mi][ni] = __builtin_amdgcn_mfma_f32_16x16x32_f16(
                            bf[ni], af[mi], acc[mi][ni], 0, 0, 0);
                    else
                        acc[mi][ni] = __builtin_amdgcn_mfma_f32_16x16x32_f16(
                            af[mi], bf[ni], acc[mi][ni], 0, 0, 0);
                }
        }
    }
}

// ---------------------------------------------------------------------------
__global__ __launch_bounds__(256) void f32tof16_k(
    const float* __restrict__ in, _Float16* __restrict__ out, int n)
{
    int i = (blockIdx.x * 256 + threadIdx.x) * 4;
    if (i < n) {
        float4 f = *(const float4*)(in + i);
        half4 h = { (_Float16)f.x, (_Float16)f.y, (_Float16)f.z, (_Float16)f.w };
        *(half4*)(out + i) = h;
    }
}

__global__ __launch_bounds__(256) void wconv_k(
    const float* __restrict__ Wq, const float* __restrict__ Wk,
    const float* __restrict__ Wv, _Float16* __restrict__ out)
{
    const float* src = (blockIdx.y == 0) ? Wq : (blockIdx.y == 1) ? Wk : Wv;
    int i = (blockIdx.x * 256 + threadIdx.x) * 4;
    float4 f = *(const float4*)(src + i);
    half4 h = { (_Float16)f.x, (_Float16)f.y, (_Float16)f.z, (_Float16)f.w };
    *(half4*)(out + (size_t)blockIdx.y * 1024 * 1024 + i) = h;
}

// ---------------------------------------------------------------------------
// Fused QKV: 128^2 tiles, grid (64,8,3) = 1536 blocks (R5 config, proven).
// z=0 Q[t][d], z=1 K[s][d] (swapped, half4 along d); z=2 Vt[b][d][t]
// (unswapped, half4 along t).
// ---------------------------------------------------------------------------
__global__ __launch_bounds__(256) void qkv_gemm_k(
    const _Float16* __restrict__ xh, const _Float16* __restrict__ Wh,
    _Float16* __restrict__ Q, _Float16* __restrict__ K, _Float16* __restrict__ Vt)
{
    __shared__ __align__(16) _Float16 ldsA[128 * 64];
    __shared__ __align__(16) _Float16 ldsB[128 * 64];
    const int tileM = blockIdx.x * 128;
    const int tileN = blockIdx.y * 128;
    const int z     = blockIdx.z;
    const _Float16* W = Wh + (size_t)z * 1024 * 1024;

    const int lane = threadIdx.x & 63;
    const int w    = threadIdx.x >> 6;
    const int wm = w & 1, wn = w >> 1;           // WM=2, WN=2 (w%2, w/2)
    const int lr = lane & 15, lq = lane >> 4;

    if (z == 2) {
        f32x4 acc[4][4] = {};
        gemm_nt_core<128, 128, 2, 2, false>(xh + (size_t)tileM * 1024,
                                            W + (size_t)tileN * 1024,
                                            1024, 1024, 0, 1024, ldsA, ldsB, acc);
#pragma unroll
        for (int mi = 0; mi < 4; ++mi)
#pragma unroll
            for (int ni = 0; ni < 4; ++ni) {
                int m0 = tileM + wm * 64 + mi * 16 + lq * 4;
                int n  = tileN + wn * 64 + ni * 16 + lr;
                int b = m0 >> 11, tt = m0 & 2047;
                half4 h = { (_Float16)acc[mi][ni][0], (_Float16)acc[mi][ni][1],
                            (_Float16)acc[mi][ni][2], (_Float16)acc[mi][ni][3] };
                *(half4*)(Vt + (size_t)b * 2048 * 1024 + (size_t)n * 2048 + tt) = h;
            }
    } else {
        f32x4 acc[4][4] = {};
        gemm_nt_core<128, 128, 2, 2, true>(xh + (size_t)tileM * 1024,
                                           W + (size_t)tileN * 1024,
                                           1024, 1024, 0, 1024, ldsA, ldsB, acc);
        _Float16* O = (z == 0) ? Q : K;
#pragma unroll
        for (int mi = 0; mi < 4; ++mi)
#pragma unroll
            for (int ni = 0; ni < 4; ++ni) {
                int tt = tileM + wm * 64 + mi * 16 + lr;
                int d0 = tileN + wn * 64 + ni * 16 + lq * 4;
                half4 h = { (_Float16)acc[mi][ni][0], (_Float16)acc[mi][ni][1],
                            (_Float16)acc[mi][ni][2], (_Float16)acc[mi][ni][3] };
                *(half4*)(O + (size_t)tt * 1024 + d0) = h;
            }
    }
}

// ---------------------------------------------------------------------------
// Scores split-K: grid (16,16,8), z = b*2+kh, each block K in
// [kh*512, kh*512+512). Writes S1 (kh=0) or S2 (kh=1); softmax sums them.
// No causal select needed (softmax masks s<=t). 1088 uniform blocks.
// ---------------------------------------------------------------------------
__global__ __launch_bounds__(256) void scores_gemm_k(
    const _Float16* __restrict__ Q, const _Float16* __restrict__ K,
    _Float16* __restrict__ S)      // S1 at S, S2 at S + 16M halves
{
    const int ti = blockIdx.x, si = blockIdx.y;
    if (si > ti) return;                     // fully above diagonal
    const int b  = blockIdx.z >> 1;
    const int kh = blockIdx.z & 1;
    const int tileT = ti * 128, tileS = si * 128;

    __shared__ __align__(16) _Float16 ldsA[128 * 64];
    __shared__ __align__(16) _Float16 ldsB[128 * 64];
    f32x4 acc[4][4] = {};
    gemm_nt_core<128, 128, 2, 2, true>(
        Q + (size_t)b * 2048 * 1024 + (size_t)tileT * 1024,
        K + (size_t)b * 2048 * 1024 + (size_t)tileS * 1024,
        1024, 1024, kh * 512, kh * 512 + 512, ldsA, ldsB, acc);

    const int lane = threadIdx.x & 63;
    const int w    = threadIdx.x >> 6;
    const int wm = w & 1, wn = w >> 1;
    const int lr = lane & 15, lq = lane >> 4;
    const float scale = 0.03125f;  // 1024^-0.5

    _Float16* Sout = S + (size_t)kh * 16777216;   // 32 MiB apart

#pragma unroll
    for (int mi = 0; mi < 4; ++mi)
#pragma unroll
        for (int ni = 0; ni < 4; ++ni) {
            int tt = tileT + wm * 64 + mi * 16 + lr;
            int s0 = tileS + wn * 64 + ni * 16 + lq * 4;
            half4 h = { (_Float16)(acc[mi][ni][0] * scale),
                        (_Float16)(acc[mi][ni][1] * scale),
                        (_Float16)(acc[mi][ni][2] * scale),
                        (_Float16)(acc[mi][ni][3] * scale) };
            *(half4*)(Sout + ((size_t)b * 2048 + tt) * 2048 + s0) = h;
        }
}

// ---------------------------------------------------------------------------
// Softmax: one wave per row; reads S1+S2, sums, masks s<=t, writes
// normalized P back into S1 (zero-fill s>t). No LDS, no block barriers.
// ---------------------------------------------------------------------------
__global__ __launch_bounds__(256) void softmax_k(_Float16* __restrict__ S)
{
    const int w    = threadIdx.x >> 6;
    const int lane = threadIdx.x & 63;
    const int t    = blockIdx.x * 4 + w;
    const int b    = blockIdx.y;
    _Float16* row1 = S + ((size_t)b * 2048 + t) * 2048;
    _Float16* row2 = row1 + 16777216;

    float x[32];
    float mx = -1e30f;
#pragma unroll
    for (int j = 0; j < 4; ++j) {
        half8 h1 = *(const half8*)(row1 + j * 512 + lane * 8);
        half8 h2 = *(const half8*)(row2 + j * 512 + lane * 8);
#pragma unroll
        for (int e = 0; e < 8; ++e) {
            int s = j * 512 + lane * 8 + e;
            float f = (s <= t) ? ((float)h1[e] + (float)h2[e]) : -1e30f;
            x[j * 8 + e] = f;
            mx = fmaxf(mx, f);
        }
    }
#pragma unroll
    for (int o = 32; o > 0; o >>= 1) mx = fmaxf(mx, __shfl_xor(mx, o));

    float sum = 0.f;
#pragma unroll
    for (int i = 0; i < 32; ++i) {
        float e = __expf(x[i] - mx);   // masked: exp(-huge) -> 0
        x[i] = e;
        sum += e;
    }
#pragma unroll
    for (int o = 32; o > 0; o >>= 1) sum += __shfl_xor(sum, o);
    const float inv = 1.0f / sum;

#pragma unroll
    for (int j = 0; j < 4; ++j) {
        half8 p;
#pragma unroll
        for (int e = 0; e < 8; ++e) p[e] = (_Float16)(x[j * 8 + e] * inv);
        *(half8*)(row1 + j * 512 + lane * 8) = p;
    }
}

// ---------------------------------------------------------------------------
// PV split-s: grid (32,8,4): x encodes (t-tile, s-half) longest-first
// (ti = 15-(x>>1), half = x&1), y = 128-wide d-tile, z = b. Each t-tile's
// causal K-range [0, tileT+128) splits into two halves (each mult of 64).
// half 0 -> float4 into d_out; half 1 -> half4 into fp16 partial buffer.
// ---------------------------------------------------------------------------
__global__ __launch_bounds__(256) void pv_gemm_k(
    const _Float16* __restrict__ P, const _Float16* __restrict__ Vt,
    float* __restrict__ out, _Float16* __restrict__ opart)
{
    __shared__ __align__(16) _Float16 ldsA[128 * 64];
    __shared__ __align__(16) _Float16 ldsB[128 * 64];
    const int ti    = 15 - (blockIdx.x >> 1);
    const int half  = blockIdx.x & 1;
    const int tileT = ti * 128;
    const int tileD = blockIdx.y * 128;
    const int b     = blockIdx.z;
    const int kHalf = (tileT + 128) >> 1;        // multiple of 64
    const int k0 = half * kHalf, k1 = k0 + kHalf;

    f32x4 acc[4][4] = {};
    gemm_nt_core<128, 128, 2, 2, true>(
        P + ((size_t)b * 2048 + tileT) * 2048,
        Vt + (size_t)b * 1024 * 2048 + (size_t)tileD * 2048,
        2048, 2048, k0, k1, ldsA, ldsB, acc);

    const int lane = threadIdx.x & 63;
    const int w    = threadIdx.x >> 6;
    const int wm = w & 1, wn = w >> 1;
    const int lr = lane & 15, lq = lane >> 4;

    if (half == 0) {
#pragma unroll
        for (int mi = 0; mi < 4; ++mi)
#pragma unroll
            for (int ni = 0; ni < 4; ++ni) {
                int tt = tileT + wm * 64 + mi * 16 + lr;
                int d0 = tileD + wn * 64 + ni * 16 + lq * 4;
                *(f32x4*)(out + ((size_t)b * 2048 + tt) * 1024 + d0) = acc[mi][ni];
            }
    } else {
#pragma unroll
        for (int mi = 0; mi < 4; ++mi)
#pragma unroll
            for (int ni = 0; ni < 4; ++ni) {
                int tt = tileT + wm * 64 + mi * 16 + lr;
                int d0 = tileD + wn * 64 + ni * 16 + lq * 4;
                half4 h = { (_Float16)acc[mi][ni][0], (_Float16)acc[mi][ni][1],
                            (_Float16)acc[mi][ni][2], (_Float16)acc[mi][ni][3] };
                *(half4*)(opart + ((size_t)b * 2048 + tt) * 1024 + d0) = h;
            }
    }
}

// out += opart (fp16), 8.4M floats, vectorized x4.
__global__ __launch_bounds__(256) void combine_k(
    float* __restrict__ out, const _Float16* __restrict__ part)
{
    int i = (blockIdx.x * 256 + threadIdx.x) * 4;
    f32x4 o = *(f32x4*)(out + i);
    half4 p = *(const half4*)(part + i);
    o[0] += (float)p[0]; o[1] += (float)p[1];
    o[2] += (float)p[2]; o[3] += (float)p[3];
    *(f32x4*)(out + i) = o;
}

// ---------------------------------------------------------------------------
extern "C" void kernel_launch(void* const* d_in, const int* in_sizes, int n_in,
                              void* d_out, int out_size, void* d_ws, size_t ws_size,
                              hipStream_t stream)
{
    const float* x  = (const float*)d_in[0];
    const float* Wq = (const float*)d_in[1];
    const float* Wk = (const float*)d_in[2];
    const float* Wv = (const float*)d_in[3];
    float* out = (float*)d_out;

    char* ws = (char*)d_ws;
    // layout (MiB): xh 0..16 (reused as fp16 O-partial by pv) | Wh 16..22 |
    // Q 22..38 | K 38..54 | Vt 54..70 | S1 70..102 | S2 102..134.
    _Float16* xh = (_Float16*)(ws);
    _Float16* Wh = (_Float16*)(ws + (16u << 20));
    _Float16* Qh = (_Float16*)(ws + (22u << 20));
    _Float16* Kh = (_Float16*)(ws + (38u << 20));
    _Float16* Vt = (_Float16*)(ws + (54u << 20));
    _Float16* S  = (_Float16*)(ws + (70u << 20));
    _Float16* Op = xh;   // 4*2048*1024 fp16 = 16 MiB, exactly the xh region

    f32tof16_k<<<8192, 256, 0, stream>>>(x, xh, 4 * 2048 * 1024);
    wconv_k<<<dim3(1024, 3), 256, 0, stream>>>(Wq, Wk, Wv, Wh);

    qkv_gemm_k<<<dim3(64, 8, 3), 256, 0, stream>>>(xh, Wh, Qh, Kh, Vt);

    scores_gemm_k<<<dim3(16, 16, 8), 256, 0, stream>>>(Qh, Kh, S);
    softmax_k<<<dim3(512, 4), 256, 0, stream>>>(S);
    pv_gemm_k<<<dim3(32, 8, 4), 256, 0, stream>>>(S, Vt, out, Op);
    combine_k<<<8192, 256, 0, stream>>>(out, Op);
}

// Round 8
// 261.929 us; speedup vs baseline: 1.1676x; 1.0976x over previous
//
#include <hip/hip_runtime.h>
#include <hip/hip_fp16.h>

// B=4, T=2048, C=1024. Single-head causal attention, fp32 in/out.
// Internals fp16 (MFMA f32_16x16x32_f16), fp32 accum + fp32 softmax.
// R8: R5 structure (proven best: 128^2 qkv/scores, 128x64 pv, BK=64,
// single S) with REGISTER-STAGED prefetch K-loop: tile k+1 loads fly into
// VGPRs during compute(k); ds_write+barrier publishes them. Global latency
// leaves the per-iter critical path (was ~900 cyc exposed at the
// global_load_lds barrier with only 2-3 blocks/CU to overlap).

typedef __attribute__((ext_vector_type(8))) _Float16 half8;
typedef __attribute__((ext_vector_type(4))) _Float16 half4;
typedef __attribute__((ext_vector_type(4))) float f32x4;

// ---------------------------------------------------------------------------
// NT-GEMM core, TM x TN tile, BK=64, 256 thr = WM*WN waves; wave (wm,wn)
// computes (TM/WM) x (TN/WN) via FM x FN 16x16x32 MFMA frags.
// A[m][k] lda, B[n][k] ldb, k in [k0,k1) mult of 64.
// LDS swizzle (verified 0 conflicts R5): 128B rows of 8 chunks; chunk f
// holds global (row=f>>3, colchunk=(f&7)^((f>>3)&7)); fragment (row R,
// k-half h, lq) at chunk 8R + ((h*4+lq)^(R&7)).
// K-loop: reg-staged prefetch —
//   prologue: va/vb <- tile k0
//   iter k: barrier(readers done) | ds_write va/vb | issue loads k+64 ->
//           va/vb (new SSA regs, fly during compute) | barrier | compute(k)
// SWAP: mfma(b,a) -> C^T frags (4 consecutive n-cols per lane).
// ---------------------------------------------------------------------------
template<int TM, int TN, int WM, int WN, bool SWAP>
__device__ __forceinline__ void gemm_nt_core(
    const _Float16* __restrict__ A, const _Float16* __restrict__ B,
    int lda, int ldb, int k0, int k1,
    _Float16* ldsA, _Float16* ldsB,      // TM*64, TN*64 halves
    f32x4 acc[TM / (WM * 16)][TN / (WN * 16)])
{
    constexpr int FM = TM / (WM * 16), FN = TN / (WN * 16);
    constexpr int NA = TM / 32, NB = TN / 32;   // 16B chunks per thread
    const int t    = threadIdx.x;
    const int lane = t & 63;
    const int w    = t >> 6;
    const int wm   = w % WM;
    const int wn   = w / WM;
    const int lr   = lane & 15;
    const int lq   = lane >> 4;

    const _Float16* ga[NA]; int loA[NA];
    const _Float16* gb[NB]; int loB[NB];
#pragma unroll
    for (int i = 0; i < NA; ++i) {
        int f = t + 256 * i;
        int r = f >> 3, c = (f & 7) ^ ((f >> 3) & 7);
        ga[i] = A + (size_t)r * lda + c * 8;
        loA[i] = f * 8;
    }
#pragma unroll
    for (int i = 0; i < NB; ++i) {
        int f = t + 256 * i;
        int r = f >> 3, c = (f & 7) ^ ((f >> 3) & 7);
        gb[i] = B + (size_t)r * ldb + c * 8;
        loB[i] = f * 8;
    }

    int offA[2][FM], offB[2][FN];
#pragma unroll
    for (int h = 0; h < 2; ++h) {
#pragma unroll
        for (int i = 0; i < FM; ++i) {
            int R = wm * (TM / WM) + i * 16 + lr;
            offA[h][i] = (8 * R + ((h * 4 + lq) ^ (R & 7))) * 8;
        }
#pragma unroll
        for (int i = 0; i < FN; ++i) {
            int R = wn * (TN / WN) + i * 16 + lr;
            offB[h][i] = (8 * R + ((h * 4 + lq) ^ (R & 7))) * 8;
        }
    }

    // prologue: tile k0 -> registers
    half8 va[NA], vb[NB];
#pragma unroll
    for (int i = 0; i < NA; ++i) va[i] = *(const half8*)(ga[i] + k0);
#pragma unroll
    for (int i = 0; i < NB; ++i) vb[i] = *(const half8*)(gb[i] + k0);

    for (int k = k0; k < k1; k += 64) {
        __syncthreads();               // prev iter's LDS readers done
#pragma unroll
        for (int i = 0; i < NA; ++i) *(half8*)(ldsA + loA[i]) = va[i];
#pragma unroll
        for (int i = 0; i < NB; ++i) *(half8*)(ldsB + loB[i]) = vb[i];
        if (k + 64 < k1) {             // issue next tile's loads; they fly
#pragma unroll                         // during this iter's compute phase
            for (int i = 0; i < NA; ++i) va[i] = *(const half8*)(ga[i] + k + 64);
#pragma unroll
            for (int i = 0; i < NB; ++i) vb[i] = *(const half8*)(gb[i] + k + 64);
        }
        __syncthreads();               // LDS writes visible

#pragma unroll
        for (int h = 0; h < 2; ++h) {
            half8 af[FM], bf[FN];
#pragma unroll
            for (int i = 0; i < FM; ++i) af[i] = *(const half8*)(ldsA + offA[h][i]);
#pragma unroll
            for (int i = 0; i < FN; ++i) bf[i] = *(const half8*)(ldsB + offB[h][i]);
#pragma unroll
            for (int mi = 0; mi < FM; ++mi)
#pragma unroll
                for (int ni = 0; ni < FN; ++ni) {
                    if constexpr (SWAP)
                        acc[mi][ni] = __builtin_amdgcn_mfma_f32_16x16x32_f16(
                            bf[ni], af[mi], acc[mi][ni], 0, 0, 0);
                    else
                        acc[mi][ni] = __builtin_amdgcn_mfma_f32_16x16x32_f16(
                            af[mi], bf[ni], acc[mi][ni], 0, 0, 0);
                }
        }
    }
}

// ---------------------------------------------------------------------------
__global__ __launch_bounds__(256) void f32tof16_k(
    const float* __restrict__ in, _Float16* __restrict__ out, int n)
{
    int i = (blockIdx.x * 256 + threadIdx.x) * 4;
    if (i < n) {
        float4 f = *(const float4*)(in + i);
        half4 h = { (_Float16)f.x, (_Float16)f.y, (_Float16)f.z, (_Float16)f.w };
        *(half4*)(out + i) = h;
    }
}

__global__ __launch_bounds__(256) void wconv_k(
    const float* __restrict__ Wq, const float* __restrict__ Wk,
    const float* __restrict__ Wv, _Float16* __restrict__ out)
{
    const float* src = (blockIdx.y == 0) ? Wq : (blockIdx.y == 1) ? Wk : Wv;
    int i = (blockIdx.x * 256 + threadIdx.x) * 4;
    float4 f = *(const float4*)(src + i);
    half4 h = { (_Float16)f.x, (_Float16)f.y, (_Float16)f.z, (_Float16)f.w };
    *(half4*)(out + (size_t)blockIdx.y * 1024 * 1024 + i) = h;
}

// ---------------------------------------------------------------------------
// Fused QKV: 128^2 tiles, grid (64,8,3) = 1536 blocks.
// z=0 Q[t][d], z=1 K[s][d] (swapped, half4 along d); z=2 Vt[b][d][t]
// (unswapped, half4 along t).
// ---------------------------------------------------------------------------
__global__ __launch_bounds__(256) void qkv_gemm_k(
    const _Float16* __restrict__ xh, const _Float16* __restrict__ Wh,
    _Float16* __restrict__ Q, _Float16* __restrict__ K, _Float16* __restrict__ Vt)
{
    __shared__ __align__(16) _Float16 ldsA[128 * 64];
    __shared__ __align__(16) _Float16 ldsB[128 * 64];
    const int tileM = blockIdx.x * 128;
    const int tileN = blockIdx.y * 128;
    const int z     = blockIdx.z;
    const _Float16* W = Wh + (size_t)z * 1024 * 1024;

    const int lane = threadIdx.x & 63;
    const int w    = threadIdx.x >> 6;
    const int wm = w & 1, wn = w >> 1;
    const int lr = lane & 15, lq = lane >> 4;

    if (z == 2) {
        f32x4 acc[4][4] = {};
        gemm_nt_core<128, 128, 2, 2, false>(xh + (size_t)tileM * 1024,
                                            W + (size_t)tileN * 1024,
                                            1024, 1024, 0, 1024, ldsA, ldsB, acc);
#pragma unroll
        for (int mi = 0; mi < 4; ++mi)
#pragma unroll
            for (int ni = 0; ni < 4; ++ni) {
                int m0 = tileM + wm * 64 + mi * 16 + lq * 4;
                int n  = tileN + wn * 64 + ni * 16 + lr;
                int b = m0 >> 11, tt = m0 & 2047;
                half4 h = { (_Float16)acc[mi][ni][0], (_Float16)acc[mi][ni][1],
                            (_Float16)acc[mi][ni][2], (_Float16)acc[mi][ni][3] };
                *(half4*)(Vt + (size_t)b * 2048 * 1024 + (size_t)n * 2048 + tt) = h;
            }
    } else {
        f32x4 acc[4][4] = {};
        gemm_nt_core<128, 128, 2, 2, true>(xh + (size_t)tileM * 1024,
                                           W + (size_t)tileN * 1024,
                                           1024, 1024, 0, 1024, ldsA, ldsB, acc);
        _Float16* O = (z == 0) ? Q : K;
#pragma unroll
        for (int mi = 0; mi < 4; ++mi)
#pragma unroll
            for (int ni = 0; ni < 4; ++ni) {
                int tt = tileM + wm * 64 + mi * 16 + lr;
                int d0 = tileN + wn * 64 + ni * 16 + lq * 4;
                half4 h = { (_Float16)acc[mi][ni][0], (_Float16)acc[mi][ni][1],
                            (_Float16)acc[mi][ni][2], (_Float16)acc[mi][ni][3] };
                *(half4*)(O + (size_t)tt * 1024 + d0) = h;
            }
    }
}

// ---------------------------------------------------------------------------
// Scores (fp16): 128x128 tiles, grid (16,16,4), early-return above diagonal.
// Swapped MFMA -> half4 along s, causal mask to 0 in-tile.
// ---------------------------------------------------------------------------
__global__ __launch_bounds__(256) void scores_gemm_k(
    const _Float16* __restrict__ Q, const _Float16* __restrict__ K,
    _Float16* __restrict__ S)
{
    const int ti = blockIdx.x, si = blockIdx.y;
    if (si > ti) return;                     // fully above diagonal
    const int tileT = ti * 128, tileS = si * 128, b = blockIdx.z;

    __shared__ __align__(16) _Float16 ldsA[128 * 64];
    __shared__ __align__(16) _Float16 ldsB[128 * 64];
    f32x4 acc[4][4] = {};
    gemm_nt_core<128, 128, 2, 2, true>(
        Q + (size_t)b * 2048 * 1024 + (size_t)tileT * 1024,
        K + (size_t)b * 2048 * 1024 + (size_t)tileS * 1024,
        1024, 1024, 0, 1024, ldsA, ldsB, acc);

    const int lane = threadIdx.x & 63;
    const int w    = threadIdx.x >> 6;
    const int wm = w & 1, wn = w >> 1;
    const int lr = lane & 15, lq = lane >> 4;
    const float scale = 0.03125f;  // 1024^-0.5

#pragma unroll
    for (int mi = 0; mi < 4; ++mi)
#pragma unroll
        for (int ni = 0; ni < 4; ++ni) {
            int tt = tileT + wm * 64 + mi * 16 + lr;
            int s0 = tileS + wn * 64 + ni * 16 + lq * 4;
            half4 h;
#pragma unroll
            for (int r = 0; r < 4; ++r)
                h[r] = (s0 + r <= tt) ? (_Float16)(acc[mi][ni][r] * scale)
                                      : (_Float16)0.f;
            *(half4*)(S + ((size_t)b * 2048 + tt) * 2048 + s0) = h;
        }
}

// ---------------------------------------------------------------------------
// Softmax: one wave per row, half8 loads, 64-lane shuffle reduce, no LDS,
// no block barriers. In-tile s>t already 0 from scores; PV never reads
// beyond its kEnd.
// ---------------------------------------------------------------------------
__global__ __launch_bounds__(256) void softmax_k(_Float16* __restrict__ S)
{
    const int w    = threadIdx.x >> 6;
    const int lane = threadIdx.x & 63;
    const int t    = blockIdx.x * 4 + w;
    const int b    = blockIdx.y;
    _Float16* row = S + ((size_t)b * 2048 + t) * 2048;

    float x[32];
    float mx = -1e30f;
#pragma unroll
    for (int j = 0; j < 4; ++j) {
        half8 h = *(const half8*)(row + j * 512 + lane * 8);
#pragma unroll
        for (int e = 0; e < 8; ++e) {
            int s = j * 512 + lane * 8 + e;
            float f = (s <= t) ? (float)h[e] : -1e30f;
            x[j * 8 + e] = f;
            mx = fmaxf(mx, f);
        }
    }
#pragma unroll
    for (int o = 32; o > 0; o >>= 1) mx = fmaxf(mx, __shfl_xor(mx, o));

    float sum = 0.f;
#pragma unroll
    for (int i = 0; i < 32; ++i) {
        float e = __expf(x[i] - mx);   // masked: exp(-huge) -> 0
        x[i] = e;
        sum += e;
    }
#pragma unroll
    for (int o = 32; o > 0; o >>= 1) sum += __shfl_xor(sum, o);
    const float inv = 1.0f / sum;

#pragma unroll
    for (int j = 0; j < 4; ++j) {
        half8 p;
#pragma unroll
        for (int e = 0; e < 8; ++e) p[e] = (_Float16)(x[j * 8 + e] * inv);
        *(half8*)(row + j * 512 + lane * 8) = p;
    }
}

// ---------------------------------------------------------------------------
// PV: 128(t) x 64(d) tiles -> grid (16,16,4) = 1024 blocks, kEnd = tileT+128.
// Longest t-tiles first. Swapped MFMA -> float4 along d.
// ---------------------------------------------------------------------------
__global__ __launch_bounds__(256) void pv_gemm_k(
    const _Float16* __restrict__ P, const _Float16* __restrict__ Vt,
    float* __restrict__ out)
{
    __shared__ __align__(16) _Float16 ldsA[128 * 64];
    __shared__ __align__(16) _Float16 ldsB[64 * 64];
    const int tileT = (15 - blockIdx.x) * 128;   // longest-first
    const int tileD = blockIdx.y * 64;
    const int b     = blockIdx.z;
    const int kEnd  = tileT + 128;

    f32x4 acc[4][2] = {};
    gemm_nt_core<128, 64, 2, 2, true>(
        P + ((size_t)b * 2048 + tileT) * 2048,
        Vt + (size_t)b * 1024 * 2048 + (size_t)tileD * 2048,
        2048, 2048, 0, kEnd, ldsA, ldsB, acc);

    const int lane = threadIdx.x & 63;
    const int w    = threadIdx.x >> 6;
    const int wm = w & 1, wn = w >> 1;
    const int lr = lane & 15, lq = lane >> 4;

#pragma unroll
    for (int mi = 0; mi < 4; ++mi)
#pragma unroll
        for (int ni = 0; ni < 2; ++ni) {
            int tt = tileT + wm * 64 + mi * 16 + lr;
            int d0 = tileD + wn * 32 + ni * 16 + lq * 4;
            *(f32x4*)(out + ((size_t)b * 2048 + tt) * 1024 + d0) = acc[mi][ni];
        }
}

// ---------------------------------------------------------------------------
extern "C" void kernel_launch(void* const* d_in, const int* in_sizes, int n_in,
                              void* d_out, int out_size, void* d_ws, size_t ws_size,
                              hipStream_t stream)
{
    const float* x  = (const float*)d_in[0];
    const float* Wq = (const float*)d_in[1];
    const float* Wk = (const float*)d_in[2];
    const float* Wv = (const float*)d_in[3];
    float* out = (float*)d_out;

    char* ws = (char*)d_ws;
    // layout (MB): xh 0..16 | Wh 16..22 | Q 22..38 | K 38..54 | Vt 54..70 |
    // S16 70..102 (P aliases S).  Total 102 MB.
    _Float16* xh = (_Float16*)(ws);
    _Float16* Wh = (_Float16*)(ws + (16u << 20));
    _Float16* Qh = (_Float16*)(ws + (22u << 20));
    _Float16* Kh = (_Float16*)(ws + (38u << 20));
    _Float16* Vt = (_Float16*)(ws + (54u << 20));
    _Float16* S  = (_Float16*)(ws + (70u << 20));

    f32tof16_k<<<8192, 256, 0, stream>>>(x, xh, 4 * 2048 * 1024);
    wconv_k<<<dim3(1024, 3), 256, 0, stream>>>(Wq, Wk, Wv, Wh);

    qkv_gemm_k<<<dim3(64, 8, 3), 256, 0, stream>>>(xh, Wh, Qh, Kh, Vt);

    scores_gemm_k<<<dim3(16, 16, 4), 256, 0, stream>>>(Qh, Kh, S);
    softmax_k<<<dim3(512, 4), 256, 0, stream>>>(S);
    pv_gemm_k<<<dim3(16, 16, 4), 256, 0, stream>>>(S, Vt, out);
}